// Round 14
// baseline (528.870 us; speedup 1.0000x reference)
//
#include <hip/hip_runtime.h>

typedef unsigned short u16;
typedef __attribute__((ext_vector_type(4))) float f32x4;
typedef __attribute__((ext_vector_type(8))) short bf16x8;
typedef __attribute__((ext_vector_type(4))) int i32x4;
typedef __attribute__((ext_vector_type(4))) unsigned short u16x4;

#define BB 2
#define SS 2048
#define DD 1024
#define HH 16
#define DH 64
#define KK 512

// workspace layout (bytes) — total ~53 MB (<= 80.1 MB proven safe)
#define OFF_SCAL  ((size_t)0)                       // accbuf[2] f32
#define OFF_WT    ((size_t)256)                     // 5 x 1024x1024 bf16 [n][k] = 10 MB
#define OFF_XB    (OFF_WT + (size_t)5*1024*1024*2)  // x bf16 [4096][1024] = 8 MB (aliases AO)
#define OFF_AO    OFF_XB                            // attn out bf16 [4096][1024] = 8 MB
#define OFF_GG    (OFF_XB + (size_t)4096*1024*2)    // gate bf16 [4096][1024] = 8 MB
#define OFF_QN    (OFF_GG + (size_t)4096*1024*2)    // qn bf16 [B,H,S,64] = 8 MB
#define OFF_KN    (OFF_QN + (size_t)4096*1024*2)    // kn bf16 [B,H,S,64] = 8 MB
#define OFF_VT    (OFF_KN + (size_t)4096*1024*2)    // vt bf16 [B,H,64,S] = 8 MB

__device__ __forceinline__ float b2f(u16 u) { return __uint_as_float(((unsigned)u) << 16); }
__device__ __forceinline__ u16 f2b(float f) {
    unsigned u = __float_as_uint(f);
    return (u16)((u + 0x7fffu + ((u >> 16) & 1u)) >> 16);   // RNE
}

// async global->LDS, 16B per lane; LDS dest = wave-uniform base + lane*16
__device__ __forceinline__ void gload16(const u16* g, u16* l) {
    __builtin_amdgcn_global_load_lds(
        (__attribute__((address_space(1))) void*)g,
        (__attribute__((address_space(3))) void*)l, 16, 0, 0);
}

// ---------------------------------------------------------------------------
// 0) prep: convert_x + temp dot fused [0,4096) (block = one token row) +
//    transpose_w [4096,5376). One x pass total (was two).
// ---------------------------------------------------------------------------
__global__ __launch_bounds__(256) void prep(
        const float* x, const float* Wq, const float* Wk, const float* Wv,
        const float* Wg, const float* Wo, const float* Wt,
        u16* xb, u16* WT, float* accbuf) {
    __shared__ float tile[64][65];
    int bid = blockIdx.x;
    if (bid < 4096) {
        // convert x fp32 -> bf16 for row bid, and accumulate dot(x_row, Wt)
        int i = bid * 1024 + threadIdx.x * 4;
        int c = threadIdx.x * 4;
        float4 v = *(const float4*)(x + i);
        u16 r0 = f2b(v.x), r1 = f2b(v.y), r2 = f2b(v.z), r3 = f2b(v.w);
        xb[i] = r0; xb[i + 1] = r1; xb[i + 2] = r2; xb[i + 3] = r3;
        float a = v.x * Wt[c] + v.y * Wt[c + 1] + v.z * Wt[c + 2] + v.w * Wt[c + 3];
        for (int o = 32; o; o >>= 1) a += __shfl_xor(a, o);
        __shared__ float red[4];
        if ((threadIdx.x & 63) == 0) red[threadIdx.x >> 6] = a;
        __syncthreads();
        if (threadIdx.x == 0)
            atomicAdd(&accbuf[bid >> 11], red[0] + red[1] + red[2] + red[3]);
    } else {
        // transpose+convert five 1024x1024 fp32 weights into WT bf16 [n][k]
        int t = bid - 4096;
        int z = t >> 8, xy = t & 255;
        const float* src = (z == 0) ? Wq : (z == 1) ? Wk : (z == 2) ? Wv
                         : (z == 3) ? Wg : Wo;
        u16* dst = WT + (size_t)z * 1024 * 1024;
        int n0 = (xy & 15) * 64, k0 = (xy >> 4) * 64;
        int rbase = threadIdx.x >> 6, c = threadIdx.x & 63;
#pragma unroll
        for (int i = 0; i < 16; i++) {
            int r = i * 4 + rbase;
            tile[r][c] = src[(size_t)(k0 + r) * 1024 + n0 + c];
        }
        __syncthreads();
#pragma unroll
        for (int i = 0; i < 16; i++) {
            int r = i * 4 + rbase;
            dst[(size_t)(n0 + r) * 1024 + k0 + c] = f2b(tile[c][r]);
        }
    }
}

// ---------------------------------------------------------------------------
// 3) QKVG GEMM, m97 structure + T1 XCD swizzle, fused epilogue:
//    Q/K -> f32 row-norm -> qn/kn; V -> vt (packed 8B); G -> dense gg.
// ---------------------------------------------------------------------------
__global__ __launch_bounds__(256) void gemm_qkvg(
        const u16* X, const u16* WT,
        const float* bq, const float* bk, const float* bv, const float* bg,
        u16* gg, u16* qn, u16* kn, u16* vt) {
    __shared__ __align__(16) u16 la[128 * 32];   // linear (required by global_load_lds)
    __shared__ __align__(16) u16 lb[128 * 32];
    int tid = threadIdx.x, wid = tid >> 6, lane = tid & 63;
    int quad = lane >> 4, ml = lane & 15;
    int lid = blockIdx.y * 32 + blockIdx.x;
    int swz = (lid & 7) * 128 + (lid >> 3);      // bijective: 1024 = 8*128
    int m0 = (swz & 31) * 128, n0 = (swz >> 5) * 128;
    int wr = wid >> 1, wc = wid & 1;

    f32x4 acc[4][4];
#pragma unroll
    for (int i = 0; i < 4; i++)
#pragma unroll
        for (int j = 0; j < 4; j++) acc[i][j] = (f32x4){0.f, 0.f, 0.f, 0.f};

    int t0 = wid * 2, t1 = t0 + 1;
    int r0 = lane >> 2, kp = lane & 3;
    const u16* ga0 = X + (size_t)(m0 + t0 * 16 + r0) * 1024 + kp * 8;
    const u16* ga1 = X + (size_t)(m0 + t1 * 16 + r0) * 1024 + kp * 8;
    const u16* gb0 = WT + (size_t)(n0 + t0 * 16 + r0) * 1024 + kp * 8;
    const u16* gb1 = WT + (size_t)(n0 + t1 * 16 + r0) * 1024 + kp * 8;
    u16* la0 = la + t0 * 512; u16* la1 = la + t1 * 512;
    u16* lb0 = lb + t0 * 512; u16* lb1 = lb + t1 * 512;

    for (int k0 = 0; k0 < 1024; k0 += 32) {
        gload16(ga0 + k0, la0);
        gload16(ga1 + k0, la1);
        gload16(gb0 + k0, lb0);
        gload16(gb1 + k0, lb1);
        __syncthreads();
        bf16x8 af[4], bfr[4];
#pragma unroll
        for (int mi = 0; mi < 4; mi++)
            af[mi] = *(const bf16x8*)&la[(wr * 64 + mi * 16 + ml) * 32 + quad * 8];
#pragma unroll
        for (int ni = 0; ni < 4; ni++)
            bfr[ni] = *(const bf16x8*)&lb[(wc * 64 + ni * 16 + ml) * 32 + quad * 8];
#pragma unroll
        for (int mi = 0; mi < 4; mi++)
#pragma unroll
            for (int ni = 0; ni < 4; ni++)
                acc[mi][ni] = __builtin_amdgcn_mfma_f32_16x16x32_bf16(af[mi], bfr[ni],
                                                                      acc[mi][ni], 0, 0, 0);
        __syncthreads();
    }

    // ---- fused epilogue ----
    int matn = n0 >> 10;                       // 0 Q, 1 K, 2 V, 3 G (uniform per block)
    int basecol = (n0 & 1023) + wc * 64;       // within-mat col base for this wave
    int token0 = m0 + wr * 64;
    int b = token0 >> 11;                      // uniform per block (128 | 2048)
    int h = basecol >> 6;                      // head (uniform per wave)
    int bh = b * HH + h;

    if (matn == 3) {
        // gate -> dense gg [4096][1024]
#pragma unroll
        for (int mi = 0; mi < 4; mi++)
#pragma unroll
            for (int ni = 0; ni < 4; ni++) {
                int col = basecol + ni * 16 + ml;
                float bias = bg[col];
#pragma unroll
                for (int r = 0; r < 4; r++) {
                    int row = m0 + wr * 64 + mi * 16 + quad * 4 + r;
                    gg[(size_t)row * 1024 + col] = f2b(acc[mi][ni][r] + bias);
                }
            }
    } else if (matn == 2) {
        // V -> vt [bh][dh][s]; pack 4 consecutive s (r=0..3) into one 8B store
        float bias[4];
#pragma unroll
        for (int ni = 0; ni < 4; ni++) bias[ni] = bv[basecol + ni * 16 + ml];
#pragma unroll
        for (int mi = 0; mi < 4; mi++) {
            int sb = (token0 + mi * 16 + quad * 4) & 2047;
#pragma unroll
            for (int ni = 0; ni < 4; ni++) {
                int dh = ni * 16 + ml;
                u16x4 w;
#pragma unroll
                for (int r = 0; r < 4; r++) w[r] = f2b(acc[mi][ni][r] + bias[ni]);
                *(u16x4*)(vt + ((size_t)bh * DH + dh) * SS + sb) = w;
            }
        }
    } else {
        // Q or K: bias + f32 row-norm over the head's 64 cols -> qn/kn
        const float* bp = matn ? bk : bq;
        u16* dst = matn ? kn : qn;
        float bias[4];
#pragma unroll
        for (int ni = 0; ni < 4; ni++) bias[ni] = bp[basecol + ni * 16 + ml];
#pragma unroll
        for (int mi = 0; mi < 4; mi++)
#pragma unroll
            for (int r = 0; r < 4; r++) {
                float q[4];
                float ss = 0.f;
#pragma unroll
                for (int ni = 0; ni < 4; ni++) {
                    q[ni] = acc[mi][ni][r] + bias[ni];
                    ss += q[ni] * q[ni];
                }
                // reduce over the 16 ml-lanes (bits 0-3 stay within the quad)
                ss += __shfl_xor(ss, 1);
                ss += __shfl_xor(ss, 2);
                ss += __shfl_xor(ss, 4);
                ss += __shfl_xor(ss, 8);
                float rn = 1.f / fmaxf(sqrtf(ss), 1e-12f);
                int s = (token0 + mi * 16 + quad * 4 + r) & 2047;
                u16* rowp = dst + ((size_t)bh * SS + s) * DH;
#pragma unroll
                for (int ni = 0; ni < 4; ni++)
                    rowp[ni * 16 + ml] = f2b(q[ni] * rn);
            }
    }
}

// ---------------------------------------------------------------------------
// 5) attention — best measured configuration (~305 µs): 16 waves / 16 q-rows,
//    R3 select (ballot bit-descent, pinned keys), XCD swizzle, inline itemp.
// ---------------------------------------------------------------------------
#define EST 2088   // u16 stride: (EST/2)%32==20 -> b128 A-frag reads spread all 32 banks

__global__ __launch_bounds__(1024, 8) void attn_kernel(
        const u16* qn, const u16* kn, const u16* vt,
        const float* accbuf, const float* bt, u16* ao) {
    __shared__ __align__(16) u16 e16[16 * EST];   // 66816 B
    __shared__ float pvp[3][16][66];              // 12672 B PV partials (padded)
    __shared__ float zrow_s[16];

    int tid = threadIdx.x, wid = tid >> 6, lane = tid & 63;   // wid in [0,16)
    int quad = lane >> 4, nl = lane & 15;
    // XCD-aware bijective swizzle: 4096 blocks, 8 XCDs, 512/XCD ->
    // all 128 qt-blocks of a (b,h) land on one XCD (kn/vt L2 reuse)
    int bid = blockIdx.x;
    int swz = (bid & 7) * 512 + (bid >> 3);
    int bh = swz >> 7, qt = swz & 127;
    int b = bh >> 4, h = bh & 15;
    const u16* qbase = qn + ((size_t)bh * SS + qt * 16) * DH;
    const u16* kbase = kn + (size_t)bh * SS * DH;
    const u16* vbase = vt + (size_t)bh * DH * SS;
    // inline adaptive temperature (prep's accbuf is complete)
    float av = accbuf[b] * (1.f / (float)SS) + bt[0];
    float tmp = 1.f / (1.f + __expf(-av)) + 0.5f;
    float it = 1.f / tmp;

    // q A-fragments: lane holds q[m=nl][k=quad*8+j (+32)]
    bf16x8 aq0 = *(const bf16x8*)(qbase + nl * DH + quad * 8);
    bf16x8 aq1 = *(const bf16x8*)(qbase + nl * DH + 32 + quad * 8);

    // ---- scores: wave wid covers cols wid*16+nl (mod 256), 8 chunks ----
#pragma unroll 4
    for (int c = 0; c < 8; c++) {
        int j = c * 256 + wid * 16 + nl;
        const u16* kr = kbase + (size_t)j * DH;
        bf16x8 b0 = *(const bf16x8*)(kr + quad * 8);
        bf16x8 b1 = *(const bf16x8*)(kr + 32 + quad * 8);
        f32x4 acc = (f32x4){0.f, 0.f, 0.f, 0.f};
        __builtin_amdgcn_s_setprio(1);
        acc = __builtin_amdgcn_mfma_f32_16x16x32_bf16(aq0, b0, acc, 0, 0, 0);
        acc = __builtin_amdgcn_mfma_f32_16x16x32_bf16(aq1, b1, acc, 0, 0, 0);
        __builtin_amdgcn_s_setprio(0);
#pragma unroll
        for (int r = 0; r < 4; r++) e16[(quad * 4 + r) * EST + j] = f2b(acc[r] * it);
    }
    __syncthreads();

    // ---- select: wave wid owns row wid; keys pinned resident in VGPRs ----
    {
        u16* rp = &e16[wid * EST];
        int kk[32];
#pragma unroll
        for (int i = 0; i < 4; i++) {
            i32x4 kv = *(const i32x4*)(rp + i * 512 + lane * 8);
#pragma unroll
            for (int j = 0; j < 4; j++) {
                unsigned r2 = (unsigned)kv[j];
                // packed monotone transform (per-half, carry-free) — R1-proven
                unsigned t = ((r2 >> 15) & 0x00010001u) * 0x7FFFu;
                unsigned key2 = r2 ^ 0x80008000u ^ t;
                int lo = (int)(key2 & 0xFFFFu), hi = (int)(key2 >> 16);
                // volatile pin: output must materialize, cannot be remat'd
                asm volatile("v_mov_b32 %0, %1" : "=v"(kk[i * 8 + j * 2]) : "v"(lo));
                asm volatile("v_mov_b32 %0, %1" : "=v"(kk[i * 8 + j * 2 + 1]) : "v"(hi));
            }
        }

        int P = 0;
        for (int bit = 15; bit >= 0; bit--) {
            int cand = P | (1 << bit);
            int c0 = 0, c1 = 0, c2 = 0, c3 = 0;
#pragma unroll
            for (int c = 0; c < 32; c += 4) {
                c0 += (int)__popcll(__ballot(kk[c] >= cand));
                c1 += (int)__popcll(__ballot(kk[c + 1] >= cand));
                c2 += (int)__popcll(__ballot(kk[c + 2] >= cand));
                c3 += (int)__popcll(__ballot(kk[c + 3] >= cand));
            }
            int cnt = (c0 + c1) + (c2 + c3);
            if (cnt >= KK) P = cand;
            if (cnt == KK) break;   // exact top-KK set found
        }

        // exp (m=0: |s| < ~2.02, no overflow) + Z, packed writeback (R1-proven)
        float z = 0.f;
#pragma unroll
        for (int i = 0; i < 4; i++) {
            i32x4 ev;
#pragma unroll
            for (int j = 0; j < 4; j++) {
                int k0i = kk[i * 8 + j * 2], k1i = kk[i * 8 + j * 2 + 1];
                unsigned r0 = (unsigned)k0i ^ ((k0i & 0x8000) ? 0x8000u : 0xFFFFu);
                unsigned r1 = (unsigned)k1i ^ ((k1i & 0x8000) ? 0x8000u : 0xFFFFu);
                float f0 = __uint_as_float(r0 << 16);
                float f1 = __uint_as_float(r1 << 16);
                float e0 = (k0i >= P) ? __expf(f0) : 0.f;
                float e1 = (k1i >= P) ? __expf(f1) : 0.f;
                z += e0 + e1;
                int pw;
                asm("v_cvt_pk_bf16_f32 %0, %1, %2" : "=v"(pw) : "v"(e0), "v"(e1));
                ev[j] = pw;
            }
            *(i32x4*)(rp + i * 512 + lane * 8) = ev;
        }
#pragma unroll
        for (int o = 32; o; o >>= 1) z += __shfl_xor(z, o);
        if (lane == 0) zrow_s[wid] = z;
    }
    __syncthreads();

    // ---- PV: wave = (K-quarter kq = wid>>2, dh-group g = wid&3) ----
    f32x4 accp = (f32x4){0.f, 0.f, 0.f, 0.f};
    int kq = wid >> 2, g = wid & 3;
    int dh = g * 16 + nl;
    const u16* vrow = vbase + (size_t)dh * SS;
#pragma unroll 4
    for (int c = 0; c < 8; c++) {
        int j0 = kq * 512 + c * 64;
#pragma unroll
        for (int ks = 0; ks < 2; ks++) {
            bf16x8 a = *(const bf16x8*)&e16[nl * EST + j0 + ks * 32 + quad * 8];
            bf16x8 bfr = *(const bf16x8*)(vrow + j0 + ks * 32 + quad * 8);
            __builtin_amdgcn_s_setprio(1);
            accp = __builtin_amdgcn_mfma_f32_16x16x32_bf16(a, bfr, accp, 0, 0, 0);
            __builtin_amdgcn_s_setprio(0);
        }
    }
    if (kq) {
#pragma unroll
        for (int r = 0; r < 4; r++) pvp[kq - 1][quad * 4 + r][dh] = accp[r];
    }
    __syncthreads();
    if (kq == 0) {
#pragma unroll
        for (int r = 0; r < 4; r++) {
            int q = quad * 4 + r;
            float val = (accp[r] + pvp[0][q][dh] + pvp[1][q][dh] + pvp[2][q][dh]) / zrow_s[q];
            size_t row = (size_t)(b * SS + qt * 16 + q);
            ao[row * DD + h * 64 + dh] = f2b(val);
        }
    }
}

// ---------------------------------------------------------------------------
// 6) out = attn_out @ Wo + bo, highway: gate*out + (1-gate)*x -> fp32.
//    T1 XCD swizzle; gate from dense gg [4096][1024].
// ---------------------------------------------------------------------------
__global__ __launch_bounds__(256) void gemm_out(
        const u16* AO, const u16* WTo, const float* bo,
        const u16* gg, const float* x, float* out) {
    __shared__ __align__(16) u16 la[128 * 32];
    __shared__ __align__(16) u16 lb[128 * 32];
    int tid = threadIdx.x, wid = tid >> 6, lane = tid & 63;
    int quad = lane >> 4, ml = lane & 15;
    int lid = blockIdx.y * 32 + blockIdx.x;
    int swz = (lid & 7) * 32 + (lid >> 3);       // bijective: 256 = 8*32
    int m0 = (swz & 31) * 128, n0 = (swz >> 5) * 128;
    int wr = wid >> 1, wc = wid & 1;

    f32x4 acc[4][4];
#pragma unroll
    for (int i = 0; i < 4; i++)
#pragma unroll
        for (int j = 0; j < 4; j++) acc[i][j] = (f32x4){0.f, 0.f, 0.f, 0.f};

    int t0 = wid * 2, t1 = t0 + 1;
    int r0 = lane >> 2, kp = lane & 3;
    const u16* ga0 = AO + (size_t)(m0 + t0 * 16 + r0) * 1024 + kp * 8;
    const u16* ga1 = AO + (size_t)(m0 + t1 * 16 + r0) * 1024 + kp * 8;
    const u16* gb0 = WTo + (size_t)(n0 + t0 * 16 + r0) * 1024 + kp * 8;
    const u16* gb1 = WTo + (size_t)(n0 + t1 * 16 + r0) * 1024 + kp * 8;
    u16* la0 = la + t0 * 512; u16* la1 = la + t1 * 512;
    u16* lb0 = lb + t0 * 512; u16* lb1 = lb + t1 * 512;

    for (int k0 = 0; k0 < 1024; k0 += 32) {
        gload16(ga0 + k0, la0);
        gload16(ga1 + k0, la1);
        gload16(gb0 + k0, lb0);
        gload16(gb1 + k0, lb1);
        __syncthreads();
        bf16x8 af[4], bfr[4];
#pragma unroll
        for (int mi = 0; mi < 4; mi++)
            af[mi] = *(const bf16x8*)&la[(wr * 64 + mi * 16 + ml) * 32 + quad * 8];
#pragma unroll
        for (int ni = 0; ni < 4; ni++)
            bfr[ni] = *(const bf16x8*)&lb[(wc * 64 + ni * 16 + ml) * 32 + quad * 8];
#pragma unroll
        for (int mi = 0; mi < 4; mi++)
#pragma unroll
            for (int ni = 0; ni < 4; ni++)
                acc[mi][ni] = __builtin_amdgcn_mfma_f32_16x16x32_bf16(af[mi], bfr[ni],
                                                                      acc[mi][ni], 0, 0, 0);
        __syncthreads();
    }

#pragma unroll
    for (int mi = 0; mi < 4; mi++)
#pragma unroll
        for (int ni = 0; ni < 4; ni++) {
            int col = n0 + wc * 64 + ni * 16 + ml;
            float bias = bo[col];
#pragma unroll
            for (int r = 0; r < 4; r++) {
                int row = m0 + wr * 64 + mi * 16 + quad * 4 + r;
                float gv = b2f(gg[(size_t)row * 1024 + col]);
                float gate = 1.f / (1.f + __expf(-gv));
                float xv = x[(size_t)row * 1024 + col];
                float o = acc[mi][ni][r] + bias;
                out[(size_t)row * 1024 + col] = gate * o + (1.f - gate) * xv;
            }
        }
}

// ---------------------------------------------------------------------------
extern "C" void kernel_launch(void* const* d_in, const int* in_sizes, int n_in,
                              void* d_out, int out_size, void* d_ws, size_t ws_size,
                              hipStream_t stream) {
    const float* x  = (const float*)d_in[0];
    const float* Wq = (const float*)d_in[1];
    const float* bq = (const float*)d_in[2];
    const float* Wk = (const float*)d_in[3];
    const float* bk = (const float*)d_in[4];
    const float* Wv = (const float*)d_in[5];
    const float* bv = (const float*)d_in[6];
    const float* Wo = (const float*)d_in[7];
    const float* bo = (const float*)d_in[8];
    const float* Wt = (const float*)d_in[9];
    const float* bt = (const float*)d_in[10];
    const float* Wg = (const float*)d_in[11];
    const float* bg = (const float*)d_in[12];

    char* w = (char*)d_ws;
    float* accbuf = (float*)(w + OFF_SCAL);
    u16*   WT     = (u16*)(w + OFF_WT);
    u16*   xb     = (u16*)(w + OFF_XB);
    u16*   ao     = (u16*)(w + OFF_AO);   // aliases xb (disjoint lifetime)
    u16*   gg     = (u16*)(w + OFF_GG);
    u16*   qn     = (u16*)(w + OFF_QN);
    u16*   kn     = (u16*)(w + OFF_KN);
    u16*   vt     = (u16*)(w + OFF_VT);

    hipMemsetAsync(accbuf, 0, 2 * sizeof(float), stream);

    prep<<<5376, 256, 0, stream>>>(x, Wq, Wk, Wv, Wg, Wo, Wt, xb, WT, accbuf);
    gemm_qkvg<<<dim3(32, 32), 256, 0, stream>>>(xb, WT, bq, bk, bv, bg, gg, qn, kn, vt);
    attn_kernel<<<4096, 1024, 0, stream>>>(qn, kn, vt, accbuf, bt, ao);
    gemm_out<<<dim3(32, 8), 256, 0, stream>>>(ao, WT + (size_t)4 * 1024 * 1024, bo, gg, x,
                                              (float*)d_out);
}

// Round 15
// 483.272 us; speedup vs baseline: 1.0944x; 1.0944x over previous
//
#include <hip/hip_runtime.h>

typedef unsigned short u16;
typedef __attribute__((ext_vector_type(4))) float f32x4;
typedef __attribute__((ext_vector_type(8))) short bf16x8;
typedef __attribute__((ext_vector_type(4))) int i32x4;
typedef __attribute__((ext_vector_type(4))) unsigned short u16x4;

#define BB 2
#define SS 2048
#define DD 1024
#define HH 16
#define DH 64
#define KK 512

// workspace layout (bytes) — total ~77.2 MB (<= 80.1 MB proven safe in R5)
#define OFF_SCAL  ((size_t)0)                       // accbuf[2] f32
#define OFF_WT    ((size_t)256)                     // 5 x 1024x1024 bf16 [n][k] = 10 MB
#define OFF_XB    (OFF_WT + (size_t)5*1024*1024*2)  // x bf16 [4096][1024] = 8 MB (aliases AO)
#define OFF_AO    OFF_XB                            // attn out bf16 [4096][1024] = 8 MB
#define OFF_QH    (OFF_XB + (size_t)4096*1024*2)    // Qh bf16 [4096][4096] (gate region only)
#define OFF_QN    (OFF_QH + (size_t)4096*4096*2)    // qn bf16 [B,H,S,64] = 8 MB
#define OFF_KN    (OFF_QN + (size_t)4096*1024*2)    // kn bf16 [B,H,S,64] = 8 MB
#define OFF_VT    (OFF_KN + (size_t)4096*1024*2)    // vt bf16 [B,H,64,S] = 8 MB

__device__ __forceinline__ float b2f(u16 u) { return __uint_as_float(((unsigned)u) << 16); }
__device__ __forceinline__ u16 f2b(float f) {
    unsigned u = __float_as_uint(f);
    return (u16)((u + 0x7fffu + ((u >> 16) & 1u)) >> 16);   // RNE
}

// async global->LDS, 16B per lane; LDS dest = wave-uniform base + lane*16
__device__ __forceinline__ void gload16(const u16* g, u16* l) {
    __builtin_amdgcn_global_load_lds(
        (__attribute__((address_space(1))) void*)g,
        (__attribute__((address_space(3))) void*)l, 16, 0, 0);
}

// ---------------------------------------------------------------------------
// 0) prep: fused convert_x [0,4096) + transpose_w [4096,5376) +
//    temp_partial [5376,5632). (R14 showed fusing the temp dot into the
//    convert blocks — 4096 same-line cross-XCD atomics — costs ~45 µs.)
// ---------------------------------------------------------------------------
__global__ __launch_bounds__(256) void prep(
        const float* x, const float* Wq, const float* Wk, const float* Wv,
        const float* Wg, const float* Wo, const float* Wt,
        u16* xb, u16* WT, float* accbuf) {
    __shared__ float tile[64][65];
    int bid = blockIdx.x;
    if (bid < 4096) {
        // convert x fp32 -> bf16
        int i = (bid * 256 + threadIdx.x) * 4;
        float4 v = *(const float4*)(x + i);
        u16 r0 = f2b(v.x), r1 = f2b(v.y), r2 = f2b(v.z), r3 = f2b(v.w);
        xb[i] = r0; xb[i + 1] = r1; xb[i + 2] = r2; xb[i + 3] = r3;
    } else if (bid < 5376) {
        // transpose+convert five 1024x1024 fp32 weights into WT bf16 [n][k]
        int t = bid - 4096;
        int z = t >> 8, xy = t & 255;
        const float* src = (z == 0) ? Wq : (z == 1) ? Wk : (z == 2) ? Wv
                         : (z == 3) ? Wg : Wo;
        u16* dst = WT + (size_t)z * 1024 * 1024;
        int n0 = (xy & 15) * 64, k0 = (xy >> 4) * 64;
        int rbase = threadIdx.x >> 6, c = threadIdx.x & 63;
#pragma unroll
        for (int i = 0; i < 16; i++) {
            int r = i * 4 + rbase;
            tile[r][c] = src[(size_t)(k0 + r) * 1024 + n0 + c];
        }
        __syncthreads();
#pragma unroll
        for (int i = 0; i < 16; i++) {
            int r = i * 4 + rbase;
            dst[(size_t)(n0 + r) * 1024 + k0 + c] = f2b(tile[c][r]);
        }
    } else {
        // temp_partial: accbuf[b] += sum over 16 rows of x[row] . Wt
        int t = bid - 5376;
        int b = t >> 7, ch = t & 127;
        float a = 0.f;
        for (int si = 0; si < 16; si++) {
            int s = ch * 16 + si;
            const float* xr = x + ((size_t)(b * SS + s)) * DD;
#pragma unroll
            for (int k = 0; k < 4; k++) {
                int c = threadIdx.x + k * 256;
                a += xr[c] * Wt[c];
            }
        }
        for (int o = 32; o; o >>= 1) a += __shfl_xor(a, o);
        __shared__ float red[4];
        if ((threadIdx.x & 63) == 0) red[threadIdx.x >> 6] = a;
        __syncthreads();
        if (threadIdx.x == 0) atomicAdd(&accbuf[b], red[0] + red[1] + red[2] + red[3]);
    }
}

// ---------------------------------------------------------------------------
// 3) QKVG GEMM, m97 structure + T1 XCD swizzle, with norm_repack FUSED into
//    the epilogue: each 128-col tile lies in one matrix (128|1024); each
//    wave's 64-col half is one head. Q/K: bias + f32 row-norm (Σni local +
//    16-lane shfl reduce) -> qn/kn. V: bias + packed 8B stores -> vt.
//    G: bias -> Qh (gate region, read by gemm_out).
// ---------------------------------------------------------------------------
__global__ __launch_bounds__(256) void gemm_qkvg(
        const u16* X, const u16* WT,
        const float* bq, const float* bk, const float* bv, const float* bg,
        u16* Qh, u16* qn, u16* kn, u16* vt) {
    __shared__ __align__(16) u16 la[128 * 32];   // linear (required by global_load_lds)
    __shared__ __align__(16) u16 lb[128 * 32];
    int tid = threadIdx.x, wid = tid >> 6, lane = tid & 63;
    int quad = lane >> 4, ml = lane & 15;
    int lid = blockIdx.y * 32 + blockIdx.x;
    int swz = (lid & 7) * 128 + (lid >> 3);      // bijective: 1024 = 8*128
    int m0 = (swz & 31) * 128, n0 = (swz >> 5) * 128;
    int wr = wid >> 1, wc = wid & 1;

    f32x4 acc[4][4];
#pragma unroll
    for (int i = 0; i < 4; i++)
#pragma unroll
        for (int j = 0; j < 4; j++) acc[i][j] = (f32x4){0.f, 0.f, 0.f, 0.f};

    int t0 = wid * 2, t1 = t0 + 1;
    int r0 = lane >> 2, kp = lane & 3;
    const u16* ga0 = X + (size_t)(m0 + t0 * 16 + r0) * 1024 + kp * 8;
    const u16* ga1 = X + (size_t)(m0 + t1 * 16 + r0) * 1024 + kp * 8;
    const u16* gb0 = WT + (size_t)(n0 + t0 * 16 + r0) * 1024 + kp * 8;
    const u16* gb1 = WT + (size_t)(n0 + t1 * 16 + r0) * 1024 + kp * 8;
    u16* la0 = la + t0 * 512; u16* la1 = la + t1 * 512;
    u16* lb0 = lb + t0 * 512; u16* lb1 = lb + t1 * 512;

    for (int k0 = 0; k0 < 1024; k0 += 32) {
        gload16(ga0 + k0, la0);
        gload16(ga1 + k0, la1);
        gload16(gb0 + k0, lb0);
        gload16(gb1 + k0, lb1);
        __syncthreads();
        bf16x8 af[4], bfr[4];
#pragma unroll
        for (int mi = 0; mi < 4; mi++)
            af[mi] = *(const bf16x8*)&la[(wr * 64 + mi * 16 + ml) * 32 + quad * 8];
#pragma unroll
        for (int ni = 0; ni < 4; ni++)
            bfr[ni] = *(const bf16x8*)&lb[(wc * 64 + ni * 16 + ml) * 32 + quad * 8];
#pragma unroll
        for (int mi = 0; mi < 4; mi++)
#pragma unroll
            for (int ni = 0; ni < 4; ni++)
                acc[mi][ni] = __builtin_amdgcn_mfma_f32_16x16x32_bf16(af[mi], bfr[ni],
                                                                      acc[mi][ni], 0, 0, 0);
        __syncthreads();
    }

    // ---- fused epilogue ----
    int matn = n0 >> 10;                       // 0 Q, 1 K, 2 V, 3 G (uniform per block)
    int basecol = (n0 & 1023) + wc * 64;       // within-mat col base for this wave
    int token0 = m0 + wr * 64;
    int b = token0 >> 11;                      // uniform per block (128 | 2048)
    int h = basecol >> 6;                      // head (uniform per wave)
    int bh = b * HH + h;

    if (matn == 3) {
        // gate -> Qh (layout read by gemm_out)
#pragma unroll
        for (int mi = 0; mi < 4; mi++)
#pragma unroll
            for (int ni = 0; ni < 4; ni++) {
                int col = n0 + wc * 64 + ni * 16 + ml;
                float bias = bg[col & 1023];
#pragma unroll
                for (int r = 0; r < 4; r++) {
                    int row = m0 + wr * 64 + mi * 16 + quad * 4 + r;
                    Qh[(size_t)row * 4096 + col] = f2b(acc[mi][ni][r] + bias);
                }
            }
    } else if (matn == 2) {
        // V -> vt [bh][dh][s]; pack 4 consecutive s (r=0..3) into one 8B store
        float bias[4];
#pragma unroll
        for (int ni = 0; ni < 4; ni++) bias[ni] = bv[basecol + ni * 16 + ml];
#pragma unroll
        for (int mi = 0; mi < 4; mi++) {
            int sb = (token0 + mi * 16 + quad * 4) & 2047;
#pragma unroll
            for (int ni = 0; ni < 4; ni++) {
                int dh = ni * 16 + ml;
                u16x4 w;
#pragma unroll
                for (int r = 0; r < 4; r++) w[r] = f2b(acc[mi][ni][r] + bias[ni]);
                *(u16x4*)(vt + ((size_t)bh * DH + dh) * SS + sb) = w;
            }
        }
    } else {
        // Q or K: bias + f32 row-norm over the head's 64 cols -> qn/kn
        const float* bp = matn ? bk : bq;
        u16* dst = matn ? kn : qn;
        float bias[4];
#pragma unroll
        for (int ni = 0; ni < 4; ni++) bias[ni] = bp[basecol + ni * 16 + ml];
#pragma unroll
        for (int mi = 0; mi < 4; mi++)
#pragma unroll
            for (int r = 0; r < 4; r++) {
                float q[4];
                float ss = 0.f;
#pragma unroll
                for (int ni = 0; ni < 4; ni++) {
                    q[ni] = acc[mi][ni][r] + bias[ni];
                    ss += q[ni] * q[ni];
                }
                // reduce over the 16 ml-lanes (bits 0-3 stay within the quad)
                ss += __shfl_xor(ss, 1);
                ss += __shfl_xor(ss, 2);
                ss += __shfl_xor(ss, 4);
                ss += __shfl_xor(ss, 8);
                float rn = 1.f / fmaxf(sqrtf(ss), 1e-12f);
                int s = (token0 + mi * 16 + quad * 4 + r) & 2047;
                u16* rowp = dst + ((size_t)bh * SS + s) * DH;
#pragma unroll
                for (int ni = 0; ni < 4; ni++)
                    rowp[ni * 16 + ml] = f2b(q[ni] * rn);
            }
    }
}

// ---------------------------------------------------------------------------
// 5) attention — best measured configuration (~305-310 µs): 16 waves /
//    16 q-rows, R3 select (ballot bit-descent, pinned keys), XCD swizzle,
//    inline itemp. 7 select variants + occupancy restructure all measured
//    equal or worse: issue-structure-bound at 2 blocks/CU.
// ---------------------------------------------------------------------------
#define EST 2088   // u16 stride: (EST/2)%32==20 -> b128 A-frag reads spread all 32 banks

__global__ __launch_bounds__(1024, 8) void attn_kernel(
        const u16* qn, const u16* kn, const u16* vt,
        const float* accbuf, const float* bt, u16* ao) {
    __shared__ __align__(16) u16 e16[16 * EST];   // 66816 B
    __shared__ float pvp[3][16][66];              // 12672 B PV partials (padded)
    __shared__ float zrow_s[16];

    int tid = threadIdx.x, wid = tid >> 6, lane = tid & 63;   // wid in [0,16)
    int quad = lane >> 4, nl = lane & 15;
    // XCD-aware bijective swizzle: 4096 blocks, 8 XCDs, 512/XCD ->
    // all 128 qt-blocks of a (b,h) land on one XCD (kn/vt L2 reuse)
    int bid = blockIdx.x;
    int swz = (bid & 7) * 512 + (bid >> 3);
    int bh = swz >> 7, qt = swz & 127;
    int b = bh >> 4, h = bh & 15;
    const u16* qbase = qn + ((size_t)bh * SS + qt * 16) * DH;
    const u16* kbase = kn + (size_t)bh * SS * DH;
    const u16* vbase = vt + (size_t)bh * DH * SS;
    // inline adaptive temperature (prep's accbuf is complete)
    float av = accbuf[b] * (1.f / (float)SS) + bt[0];
    float tmp = 1.f / (1.f + __expf(-av)) + 0.5f;
    float it = 1.f / tmp;

    // q A-fragments: lane holds q[m=nl][k=quad*8+j (+32)]
    bf16x8 aq0 = *(const bf16x8*)(qbase + nl * DH + quad * 8);
    bf16x8 aq1 = *(const bf16x8*)(qbase + nl * DH + 32 + quad * 8);

    // ---- scores: wave wid covers cols wid*16+nl (mod 256), 8 chunks ----
#pragma unroll 4
    for (int c = 0; c < 8; c++) {
        int j = c * 256 + wid * 16 + nl;
        const u16* kr = kbase + (size_t)j * DH;
        bf16x8 b0 = *(const bf16x8*)(kr + quad * 8);
        bf16x8 b1 = *(const bf16x8*)(kr + 32 + quad * 8);
        f32x4 acc = (f32x4){0.f, 0.f, 0.f, 0.f};
        __builtin_amdgcn_s_setprio(1);
        acc = __builtin_amdgcn_mfma_f32_16x16x32_bf16(aq0, b0, acc, 0, 0, 0);
        acc = __builtin_amdgcn_mfma_f32_16x16x32_bf16(aq1, b1, acc, 0, 0, 0);
        __builtin_amdgcn_s_setprio(0);
#pragma unroll
        for (int r = 0; r < 4; r++) e16[(quad * 4 + r) * EST + j] = f2b(acc[r] * it);
    }
    __syncthreads();

    // ---- select: wave wid owns row wid; keys pinned resident in VGPRs ----
    {
        u16* rp = &e16[wid * EST];
        int kk[32];
#pragma unroll
        for (int i = 0; i < 4; i++) {
            i32x4 kv = *(const i32x4*)(rp + i * 512 + lane * 8);
#pragma unroll
            for (int j = 0; j < 4; j++) {
                unsigned r2 = (unsigned)kv[j];
                // packed monotone transform (per-half, carry-free) — R1-proven
                unsigned t = ((r2 >> 15) & 0x00010001u) * 0x7FFFu;
                unsigned key2 = r2 ^ 0x80008000u ^ t;
                int lo = (int)(key2 & 0xFFFFu), hi = (int)(key2 >> 16);
                // volatile pin: output must materialize, cannot be remat'd
                asm volatile("v_mov_b32 %0, %1" : "=v"(kk[i * 8 + j * 2]) : "v"(lo));
                asm volatile("v_mov_b32 %0, %1" : "=v"(kk[i * 8 + j * 2 + 1]) : "v"(hi));
            }
        }

        int P = 0;
        for (int bit = 15; bit >= 0; bit--) {
            int cand = P | (1 << bit);
            int c0 = 0, c1 = 0, c2 = 0, c3 = 0;
#pragma unroll
            for (int c = 0; c < 32; c += 4) {
                c0 += (int)__popcll(__ballot(kk[c] >= cand));
                c1 += (int)__popcll(__ballot(kk[c + 1] >= cand));
                c2 += (int)__popcll(__ballot(kk[c + 2] >= cand));
                c3 += (int)__popcll(__ballot(kk[c + 3] >= cand));
            }
            int cnt = (c0 + c1) + (c2 + c3);
            if (cnt >= KK) P = cand;
            if (cnt == KK) break;   // exact top-KK set found
        }

        // exp (m=0: |s| < ~2.02, no overflow) + Z, packed writeback (R1-proven)
        float z = 0.f;
#pragma unroll
        for (int i = 0; i < 4; i++) {
            i32x4 ev;
#pragma unroll
            for (int j = 0; j < 4; j++) {
                int k0i = kk[i * 8 + j * 2], k1i = kk[i * 8 + j * 2 + 1];
                unsigned r0 = (unsigned)k0i ^ ((k0i & 0x8000) ? 0x8000u : 0xFFFFu);
                unsigned r1 = (unsigned)k1i ^ ((k1i & 0x8000) ? 0x8000u : 0xFFFFu);
                float f0 = __uint_as_float(r0 << 16);
                float f1 = __uint_as_float(r1 << 16);
                float e0 = (k0i >= P) ? __expf(f0) : 0.f;
                float e1 = (k1i >= P) ? __expf(f1) : 0.f;
                z += e0 + e1;
                int pw;
                asm("v_cvt_pk_bf16_f32 %0, %1, %2" : "=v"(pw) : "v"(e0), "v"(e1));
                ev[j] = pw;
            }
            *(i32x4*)(rp + i * 512 + lane * 8) = ev;
        }
#pragma unroll
        for (int o = 32; o; o >>= 1) z += __shfl_xor(z, o);
        if (lane == 0) zrow_s[wid] = z;
    }
    __syncthreads();

    // ---- PV: wave = (K-quarter kq = wid>>2, dh-group g = wid&3) ----
    f32x4 accp = (f32x4){0.f, 0.f, 0.f, 0.f};
    int kq = wid >> 2, g = wid & 3;
    int dh = g * 16 + nl;
    const u16* vrow = vbase + (size_t)dh * SS;
#pragma unroll 4
    for (int c = 0; c < 8; c++) {
        int j0 = kq * 512 + c * 64;
#pragma unroll
        for (int ks = 0; ks < 2; ks++) {
            bf16x8 a = *(const bf16x8*)&e16[nl * EST + j0 + ks * 32 + quad * 8];
            bf16x8 bfr = *(const bf16x8*)(vrow + j0 + ks * 32 + quad * 8);
            __builtin_amdgcn_s_setprio(1);
            accp = __builtin_amdgcn_mfma_f32_16x16x32_bf16(a, bfr, accp, 0, 0, 0);
            __builtin_amdgcn_s_setprio(0);
        }
    }
    if (kq) {
#pragma unroll
        for (int r = 0; r < 4; r++) pvp[kq - 1][quad * 4 + r][dh] = accp[r];
    }
    __syncthreads();
    if (kq == 0) {
#pragma unroll
        for (int r = 0; r < 4; r++) {
            int q = quad * 4 + r;
            float val = (accp[r] + pvp[0][q][dh] + pvp[1][q][dh] + pvp[2][q][dh]) / zrow_s[q];
            size_t row = (size_t)(b * SS + qt * 16 + q);
            ao[row * DD + h * 64 + dh] = f2b(val);
        }
    }
}

// ---------------------------------------------------------------------------
// 6) out = attn_out @ Wo + bo, highway: gate*out + (1-gate)*x -> fp32.
//    T1 XCD swizzle: 256 blocks = 8 XCDs x 32.
// ---------------------------------------------------------------------------
__global__ __launch_bounds__(256) void gemm_out(
        const u16* AO, const u16* WTo, const float* bo,
        const u16* Qh, const float* x, float* out) {
    __shared__ __align__(16) u16 la[128 * 32];
    __shared__ __align__(16) u16 lb[128 * 32];
    int tid = threadIdx.x, wid = tid >> 6, lane = tid & 63;
    int quad = lane >> 4, ml = lane & 15;
    int lid = blockIdx.y * 32 + blockIdx.x;
    int swz = (lid & 7) * 32 + (lid >> 3);       // bijective: 256 = 8*32
    int m0 = (swz & 31) * 128, n0 = (swz >> 5) * 128;
    int wr = wid >> 1, wc = wid & 1;

    f32x4 acc[4][4];
#pragma unroll
    for (int i = 0; i < 4; i++)
#pragma unroll
        for (int j = 0; j < 4; j++) acc[i][j] = (f32x4){0.f, 0.f, 0.f, 0.f};

    int t0 = wid * 2, t1 = t0 + 1;
    int r0 = lane >> 2, kp = lane & 3;
    const u16* ga0 = AO + (size_t)(m0 + t0 * 16 + r0) * 1024 + kp * 8;
    const u16* ga1 = AO + (size_t)(m0 + t1 * 16 + r0) * 1024 + kp * 8;
    const u16* gb0 = WTo + (size_t)(n0 + t0 * 16 + r0) * 1024 + kp * 8;
    const u16* gb1 = WTo + (size_t)(n0 + t1 * 16 + r0) * 1024 + kp * 8;
    u16* la0 = la + t0 * 512; u16* la1 = la + t1 * 512;
    u16* lb0 = lb + t0 * 512; u16* lb1 = lb + t1 * 512;

    for (int k0 = 0; k0 < 1024; k0 += 32) {
        gload16(ga0 + k0, la0);
        gload16(ga1 + k0, la1);
        gload16(gb0 + k0, lb0);
        gload16(gb1 + k0, lb1);
        __syncthreads();
        bf16x8 af[4], bfr[4];
#pragma unroll
        for (int mi = 0; mi < 4; mi++)
            af[mi] = *(const bf16x8*)&la[(wr * 64 + mi * 16 + ml) * 32 + quad * 8];
#pragma unroll
        for (int ni = 0; ni < 4; ni++)
            bfr[ni] = *(const bf16x8*)&lb[(wc * 64 + ni * 16 + ml) * 32 + quad * 8];
#pragma unroll
        for (int mi = 0; mi < 4; mi++)
#pragma unroll
            for (int ni = 0; ni < 4; ni++)
                acc[mi][ni] = __builtin_amdgcn_mfma_f32_16x16x32_bf16(af[mi], bfr[ni],
                                                                      acc[mi][ni], 0, 0, 0);
        __syncthreads();
    }

#pragma unroll
    for (int mi = 0; mi < 4; mi++)
#pragma unroll
        for (int ni = 0; ni < 4; ni++) {
            int col = n0 + wc * 64 + ni * 16 + ml;
            float bias = bo[col];
#pragma unroll
            for (int r = 0; r < 4; r++) {
                int row = m0 + wr * 64 + mi * 16 + quad * 4 + r;
                float gv = b2f(Qh[(size_t)row * 4096 + 3072 + col]);
                float gate = 1.f / (1.f + __expf(-gv));
                float xv = x[(size_t)row * 1024 + col];
                float o = acc[mi][ni][r] + bias;
                out[(size_t)row * 1024 + col] = gate * o + (1.f - gate) * xv;
            }
        }
}

// ---------------------------------------------------------------------------
extern "C" void kernel_launch(void* const* d_in, const int* in_sizes, int n_in,
                              void* d_out, int out_size, void* d_ws, size_t ws_size,
                              hipStream_t stream) {
    const float* x  = (const float*)d_in[0];
    const float* Wq = (const float*)d_in[1];
    const float* bq = (const float*)d_in[2];
    const float* Wk = (const float*)d_in[3];
    const float* bk = (const float*)d_in[4];
    const float* Wv = (const float*)d_in[5];
    const float* bv = (const float*)d_in[6];
    const float* Wo = (const float*)d_in[7];
    const float* bo = (const float*)d_in[8];
    const float* Wt = (const float*)d_in[9];
    const float* bt = (const float*)d_in[10];
    const float* Wg = (const float*)d_in[11];
    const float* bg = (const float*)d_in[12];

    char* w = (char*)d_ws;
    float* accbuf = (float*)(w + OFF_SCAL);
    u16*   WT     = (u16*)(w + OFF_WT);
    u16*   xb     = (u16*)(w + OFF_XB);
    u16*   ao     = (u16*)(w + OFF_AO);   // aliases xb (disjoint lifetime)
    u16*   Qh     = (u16*)(w + OFF_QH);
    u16*   qn     = (u16*)(w + OFF_QN);
    u16*   kn     = (u16*)(w + OFF_KN);
    u16*   vt     = (u16*)(w + OFF_VT);

    hipMemsetAsync(accbuf, 0, 2 * sizeof(float), stream);

    prep<<<5632, 256, 0, stream>>>(x, Wq, Wk, Wv, Wg, Wo, Wt, xb, WT, accbuf);
    gemm_qkvg<<<dim3(32, 32), 256, 0, stream>>>(xb, WT, bq, bk, bv, bg, Qh, qn, kn, vt);
    attn_kernel<<<4096, 1024, 0, stream>>>(qn, kn, vt, accbuf, bt, ao);
    gemm_out<<<dim3(32, 8), 256, 0, stream>>>(ao, WT + (size_t)4 * 1024 * 1024, bo, Qh, x,
                                              (float*)d_out);
}